// Round 7
// baseline (98.835 us; speedup 1.0000x reference)
//
#include <hip/hip_runtime.h>
#include <math.h>

// ---------------- problem constants ----------------
#define HH 120
#define WW 160
#define NPTS (HH * WW)            // 19200
#define FXC 572.4114f
#define FYC 573.57043f
#define CXC 325.2611f
#define CYC 242.04899f

// chamfer tiling
#define CH_BT   64                 // threads per block (1 wave)
#define CH_T    12                 // a-points per thread
#define CH_APB  (CH_BT * CH_T)     // 768 a-points per block
#define CH_ABLK (NPTS / CH_APB)    // 25 a-blocks
#define CH_SUB  3                  // 64-point sub-chunks per block
#define CH_CHUNK (CH_SUB * 64)     // 192 b-points per block
#define CH_SCH  (NPTS / CH_CHUNK)  // 100 b-chunks
// grid = 25 * 100 * 2 = 5000 one-wave blocks; atomics 2*19200*100 = 3.84M (as R4)

#define MASK_WGT 1.3989422804014327f   // exp(0)*inv_sqrt_2pi + 1

// finalize kernel geometry
#define GB_CH 64                   // blocks doing chamfer sum
#define GB_MK 16                   // blocks doing mask loss
#define GB_TOT (GB_CH + GB_MK)
#define CH_SEG (2 * NPTS / GB_CH)  // 600 elements per chamfer block
#define MK_SEG (NPTS / GB_MK)      // 1200 elements per mask block

typedef float __attribute__((ext_vector_type(4))) f4;

__device__ __forceinline__ void backproject_pt(int idx, float d,
                                               float& px, float& py, float& pz) {
    int y = idx / WW;
    int x = idx - y * WW;
    px = ((float)x - CXC) * d * (1.0f / FXC);
    py = ((float)y - CYC) * d * (1.0f / FYC);
    pz = d;
}

__device__ __forceinline__ float min3f(float a, float b, float c) {
    float d;
    asm("v_min3_f32 %0, %1, %2, %3" : "=v"(d) : "v"(a), "v"(b), "v"(c));
    return d;
}

// broadcast lane j's value to an SGPR (uniform); pure RF op, no memory pipe
__device__ __forceinline__ float rlane(float v, int j) {
    return __int_as_float(__builtin_amdgcn_readlane(__float_as_int(v), j));
}

// ---------------- kernel 1: precompute b-point table + init ----------------
// bp[i] = (2x, 2y, 2z, |b|^2); i < NPTS from depth_src, else depth_tgt.
__global__ void __launch_bounds__(256) prep_k(const float* __restrict__ depth_src,
                                              const float* __restrict__ depth_tgt,
                                              f4* __restrict__ bp,
                                              int* __restrict__ mins,
                                              int* __restrict__ accs) {
    int i = blockIdx.x * 256 + threadIdx.x;
    if (i < 2 * NPTS) {
        int dir = (i >= NPTS);
        int idx = i - dir * NPTS;
        float d = dir ? depth_tgt[idx] : depth_src[idx];
        float px, py, pz;
        backproject_pt(idx, d, px, py, pz);
        f4 v = {2.0f * px, 2.0f * py, 2.0f * pz,
                fmaf(px, px, fmaf(py, py, pz * pz))};
        bp[i] = v;
        mins[i] = 0x7F800000;  // +inf bit pattern
    }
    if (i < 6) accs[i] = 0;    // accf[3] + acci[3]
}

// ---------------- kernel 2: chamfer partial mins ----------------
// grid: (CH_ABLK, CH_SCH, 2). blockIdx.z selects direction.
// Steady state is pure VALU: b-points live in the wave's own VGPRs (lane j
// holds point j); v_readlane broadcasts them to SGPRs. No LDS, no SMEM, no
// barriers; one coalesced global_load_dwordx4 per 64 b-points, prefetched.
__global__ void __launch_bounds__(CH_BT, 6) chamfer_k(
    const float* __restrict__ depth_src, const float* __restrict__ depth_tgt,
    const f4* __restrict__ bp, int* __restrict__ mins_base) {
    const float* dA;
    const f4* bB;
    int* mins;
    if (blockIdx.z == 0) { dA = depth_src; bB = bp + NPTS; mins = mins_base; }
    else                 { dA = depth_tgt; bB = bp;        mins = mins_base + NPTS; }

    const int tid = threadIdx.x;
    const int ablk = blockIdx.x;
    const f4* B = bB + blockIdx.y * CH_CHUNK;

    // load a points into registers (negated for the fma chain)
    float nax[CH_T], nay[CH_T], naz[CH_T], mn[CH_T];
#pragma unroll
    for (int t = 0; t < CH_T; ++t) {
        int i = ablk * CH_APB + t * CH_BT + tid;
        float d = dA[i];
        float px, py, pz;
        backproject_pt(i, d, px, py, pz);
        nax[t] = -px; nay[t] = -py; naz[t] = -pz;
        mn[t] = INFINITY;  // tracks min over j of (b2_j - 2*dot_j)
    }

    // lane tid holds b-point (sub-chunk base + tid)
    f4 q = B[tid];
#pragma unroll
    for (int sc = 0; sc < CH_SUB; ++sc) {
        f4 qn;
        if (sc + 1 < CH_SUB) qn = B[(sc + 1) * 64 + tid];  // prefetch next
        for (int j = 0; j < 64; j += 2) {
            float sx0 = rlane(q.x, j),     sy0 = rlane(q.y, j);
            float sz0 = rlane(q.z, j),     sw0 = rlane(q.w, j);
            float sx1 = rlane(q.x, j + 1), sy1 = rlane(q.y, j + 1);
            float sz1 = rlane(q.z, j + 1), sw1 = rlane(q.w, j + 1);
#pragma unroll
            for (int t = 0; t < CH_T; ++t) {
                float r0 = fmaf(nax[t], sx0, fmaf(nay[t], sy0, fmaf(naz[t], sz0, sw0)));
                float r1 = fmaf(nax[t], sx1, fmaf(nay[t], sy1, fmaf(naz[t], sz1, sw1)));
                mn[t] = min3f(mn[t], r0, r1);
            }
        }
        q = qn;
    }

    // finalize: d = max(a2 + (b2 - 2ab), 0); a2 recomputed here (3 fma).
    // max(.,0) commutes with min; values >= 0 so int ordering == float ordering.
#pragma unroll
    for (int t = 0; t < CH_T; ++t) {
        int i = ablk * CH_APB + t * CH_BT + tid;
        float a2 = fmaf(nax[t], nax[t], fmaf(nay[t], nay[t], naz[t] * naz[t]));
        float v = fmaxf(a2 + mn[t], 0.0f);
        atomicMin(&mins[i], __float_as_int(v));
    }
}

// ---------------- kernel 3: fused reduction + mask loss -> out[0], out[1] ----------------
// accf[0]=cham_sum, accf[1]=pos_sum, accf[2]=neg_sum
// acci[0]=pos_cnt,  acci[1]=neg_cnt,  acci[2]=done_counter
__global__ void __launch_bounds__(256) finalize_k(const int* __restrict__ mins,
                                                  const float* __restrict__ pm,
                                                  const float* __restrict__ ms,
                                                  float* __restrict__ accf,
                                                  int* __restrict__ acci,
                                                  float* __restrict__ out) {
    const int b = blockIdx.x;
    const int tid = threadIdx.x;
    __shared__ float ra[256], rb[256];
    __shared__ int ca[256], cb[256];

    if (b < GB_CH) {
        // chamfer partial sum over a 600-element segment
        float s = 0.0f;
        int base = b * CH_SEG;
        for (int i = tid; i < CH_SEG; i += 256) s += __int_as_float(mins[base + i]);
        ra[tid] = s;
        __syncthreads();
        for (int w = 128; w > 0; w >>= 1) {
            if (tid < w) ra[tid] += ra[tid + w];
            __syncthreads();
        }
        if (tid == 0) atomicAdd(&accf[0], ra[0]);
    } else {
        // mask loss partial over a 1200-element segment
        int base = (b - GB_CH) * MK_SEG;
        float ps = 0.0f, ns = 0.0f;
        int pc = 0, nc = 0;
        for (int i = tid; i < MK_SEG; i += 256) {
            float p = pm[base + i];
            p = fminf(fmaxf(p, 1e-7f), 1.0f - 1e-7f);
            float t = ms[base + i];
            if (t > 0.0f) {
                ps += -t * logf(p) * MASK_WGT;
                pc++;
            } else if (t == 0.0f) {
                ns += -logf(1.0f - p) * MASK_WGT;
                nc++;
            }
        }
        ra[tid] = ps; rb[tid] = ns; ca[tid] = pc; cb[tid] = nc;
        __syncthreads();
        for (int w = 128; w > 0; w >>= 1) {
            if (tid < w) {
                ra[tid] += ra[tid + w];
                rb[tid] += rb[tid + w];
                ca[tid] += ca[tid + w];
                cb[tid] += cb[tid + w];
            }
            __syncthreads();
        }
        if (tid == 0) {
            atomicAdd(&accf[1], ra[0]);
            atomicAdd(&accf[2], rb[0]);
            atomicAdd(&acci[0], ca[0]);
            atomicAdd(&acci[1], cb[0]);
        }
    }

    // last finished block computes the final outputs
    if (tid == 0) {
        __threadfence();
        int old = __hip_atomic_fetch_add(&acci[2], 1, __ATOMIC_ACQ_REL,
                                         __HIP_MEMORY_SCOPE_AGENT);
        if (old == GB_TOT - 1) {
            __threadfence();
            float cham = __hip_atomic_load(&accf[0], __ATOMIC_RELAXED, __HIP_MEMORY_SCOPE_AGENT);
            float pos  = __hip_atomic_load(&accf[1], __ATOMIC_RELAXED, __HIP_MEMORY_SCOPE_AGENT);
            float neg  = __hip_atomic_load(&accf[2], __ATOMIC_RELAXED, __HIP_MEMORY_SCOPE_AGENT);
            int cp = __hip_atomic_load(&acci[0], __ATOMIC_RELAXED, __HIP_MEMORY_SCOPE_AGENT);
            int cn = __hip_atomic_load(&acci[1], __ATOMIC_RELAXED, __HIP_MEMORY_SCOPE_AGENT);
            out[0] = cham * (1.0f / (float)NPTS);
            float loss = 0.0f;
            if (cp > 0) loss += pos / (float)cp;
            if (cn > 0) loss += neg / (float)cn;
            out[1] = loss;
        }
    }
}

// ---------------- launcher ----------------
extern "C" void kernel_launch(void* const* d_in, const int* in_sizes, int n_in,
                              void* d_out, int out_size, void* d_ws, size_t ws_size,
                              hipStream_t stream) {
    const float* pred_PM   = (const float*)d_in[0];
    const float* pred_Ms   = (const float*)d_in[1];
    const float* depth_src = (const float*)d_in[2];
    const float* depth_tgt = (const float*)d_in[3];
    float* out = (float*)d_out;

    // workspace layout (16B-aligned pieces):
    f4* bp = (f4*)d_ws;                          // 2*NPTS float4 = 614400 B
    int* mins = (int*)(bp + 2 * NPTS);           // 2*NPTS ints   = 153600 B
    float* accf = (float*)(mins + 2 * NPTS);     // 3 floats
    int* acci = (int*)(accf + 3);                // 3 ints

    prep_k<<<(2 * NPTS + 255) / 256, 256, 0, stream>>>(depth_src, depth_tgt,
                                                       bp, mins, (int*)accf);
    chamfer_k<<<dim3(CH_ABLK, CH_SCH, 2), CH_BT, 0, stream>>>(
        depth_src, depth_tgt, bp, mins);
    finalize_k<<<GB_TOT, 256, 0, stream>>>(mins, pred_PM, pred_Ms, accf, acci, out);
}

// Round 8
// 90.281 us; speedup vs baseline: 1.0948x; 1.0948x over previous
//
#include <hip/hip_runtime.h>
#include <math.h>

// ---------------- problem constants ----------------
#define HH 120
#define WW 160
#define NPTS (HH * WW)            // 19200
#define FXC 572.4114f
#define FYC 573.57043f
#define CXC 325.2611f
#define CYC 242.04899f

// z-bucket grid (partition only -> correctness never depends on ZMIN/ZMAX)
#define NB 128
#define ZMIN 0.1f
#define ZMAX 2.1f
#define WB ((ZMAX - ZMIN) / NB)       // 0.015625
#define INVWB (NB / (ZMAX - ZMIN))    // 64.0

#define LDSN 256                  // candidate staging capacity (f4)
#define TQ 2                      // queries per lane

#define MASK_WGT 1.3989422804014327f   // exp(0)*inv_sqrt_2pi + 1
#define GB_MK 16
#define MK_SEG (NPTS / GB_MK)     // 1200

typedef float __attribute__((ext_vector_type(4))) f4;

__device__ __forceinline__ void backproject_pt(int idx, float d,
                                               float& px, float& py, float& pz) {
    int y = idx / WW;
    int x = idx - y * WW;
    px = ((float)x - CXC) * d * (1.0f / FXC);
    py = ((float)y - CYC) * d * (1.0f / FYC);
    pz = d;
}

__device__ __forceinline__ float min3f(float a, float b, float c) {
    float d;
    asm("v_min3_f32 %0, %1, %2, %3" : "=v"(d) : "v"(a), "v"(b), "v"(c));
    return d;
}

__device__ __forceinline__ int zbucket(float z) {
    int b = (int)((z - ZMIN) * INVWB);   // trunc-toward-0; clamp handles all cases
    return b < 0 ? 0 : (b > NB - 1 ? NB - 1 : b);
}

// ---------------- kernel 0: zero counters ----------------
// cnt[2*NB], cur[2*NB], accf[3], acci[3]
__global__ void __launch_bounds__(256) init_k(int* __restrict__ cnt,
                                              int* __restrict__ cur,
                                              float* __restrict__ accf,
                                              int* __restrict__ acci) {
    int t = threadIdx.x;
    cnt[t] = 0;
    cur[t] = 0;
    if (t < 3) { accf[t] = 0.0f; acci[t] = 0; }
}

// ---------------- kernel 1: backproject + z-histogram ----------------
// pts[i] = (x, y, z, |p|^2); i < NPTS from src, else tgt.
__global__ void __launch_bounds__(256) pts_hist_k(const float* __restrict__ depth_src,
                                                  const float* __restrict__ depth_tgt,
                                                  f4* __restrict__ pts,
                                                  int* __restrict__ cnt) {
    int i = blockIdx.x * 256 + threadIdx.x;
    if (i >= 2 * NPTS) return;
    int dir = (i >= NPTS);
    int idx = i - dir * NPTS;
    float d = dir ? depth_tgt[idx] : depth_src[idx];
    float px, py, pz;
    backproject_pt(idx, d, px, py, pz);
    f4 v = {px, py, pz, fmaf(px, px, fmaf(py, py, pz * pz))};
    pts[i] = v;
    atomicAdd(&cnt[dir * NB + zbucket(pz)], 1);
}

// ---------------- kernel 2: exclusive prefix scan (per cloud) ----------------
// offs[cloud*(NB+1) + b] = exclusive prefix; offs[cloud*(NB+1)+NB] = NPTS; cur = copy.
__global__ void __launch_bounds__(256) scan_k(const int* __restrict__ cnt,
                                              int* __restrict__ offs,
                                              int* __restrict__ cur) {
    __shared__ int sc[256];
    int t = threadIdx.x;          // t = cloud*NB + b
    int seg = t & (NB - 1);
    int c = cnt[t];
    sc[t] = c;
    __syncthreads();
    for (int off = 1; off < NB; off <<= 1) {
        int add = (seg >= off) ? sc[t - off] : 0;
        __syncthreads();
        sc[t] += add;
        __syncthreads();
    }
    int cloud = t >> 7;
    int excl = sc[t] - c;
    offs[cloud * (NB + 1) + seg] = excl;
    cur[t] = excl;
    if (seg == NB - 1) offs[cloud * (NB + 1) + NB] = sc[t];
}

// ---------------- kernel 3: scatter into z-sorted order ----------------
__global__ void __launch_bounds__(256) scatter_k(const f4* __restrict__ pts,
                                                 f4* __restrict__ sorted,
                                                 int* __restrict__ cur) {
    int i = blockIdx.x * 256 + threadIdx.x;
    if (i >= 2 * NPTS) return;
    int dir = (i >= NPTS);
    f4 p = pts[i];
    int b = zbucket(p.z);
    int pos = atomicAdd(&cur[dir * NB + b], 1);
    sorted[dir * NPTS + pos] = p;
}

// ---------------- kernel 4: pruned chamfer ----------------
// grid: (NB, 2, 2) = (bucket, query-half, direction); block = 64 (1 wave).
// Exact NN: scan buckets outward from center; stop when slab-edge bound beats min.
__global__ void __launch_bounds__(64) chamfer_k(const f4* __restrict__ sorted,
                                                const int* __restrict__ offs,
                                                float* __restrict__ accf) {
    const int lane = threadIdx.x;
    const int cb   = blockIdx.x;
    const int half = blockIdx.y;
    const int dir  = blockIdx.z;

    const f4* SQ = sorted + dir * NPTS;
    const f4* SB = sorted + (1 - dir) * NPTS;
    const int* offQ = offs + dir * (NB + 1);
    const int* offB = offs + (1 - dir) * (NB + 1);

    __shared__ f4 lds[LDSN];

    int q0 = offQ[cb], q1 = offQ[cb + 1];
    int qn = q1 - q0;
    int hs = qn >> 1;
    int qstart = q0 + (half ? hs : 0);
    int qcount = half ? (qn - hs) : hs;

    float wsum = 0.0f;

    for (int qc = 0; qc < qcount; qc += TQ * 64) {
        float az[TQ], a2[TQ], n2x[TQ], n2y[TQ], n2z[TQ], mn[TQ];
        bool act[TQ];
#pragma unroll
        for (int s = 0; s < TQ; ++s) {
            int qi = qc + s * 64 + lane;
            act[s] = (qi < qcount);
            f4 a = SQ[qstart + (act[s] ? qi : 0)];
            n2x[s] = -2.0f * a.x; n2y[s] = -2.0f * a.y; n2z[s] = -2.0f * a.z;
            az[s] = a.z; a2[s] = a.w;
            mn[s] = INFINITY;   // tracks min over cands of (b2 - 2*dot); d = a2 + mn
        }

        auto scan_bucket = [&](int b) {
            int c0 = offB[b], c1 = offB[b + 1];
            for (int base = c0; base < c1; base += LDSN) {
                int n = c1 - base; if (n > LDSN) n = LDSN;
                __syncthreads();   // protect lds before overwrite
                for (int k = lane; k < n; k += 64) lds[k] = SB[base + k];
                __syncthreads();
                int j = 0;
                for (; j + 1 < n; j += 2) {
                    f4 b0 = lds[j], b1 = lds[j + 1];
#pragma unroll
                    for (int s = 0; s < TQ; ++s) {
                        float r0 = fmaf(n2x[s], b0.x, fmaf(n2y[s], b0.y, fmaf(n2z[s], b0.z, b0.w)));
                        float r1 = fmaf(n2x[s], b1.x, fmaf(n2y[s], b1.y, fmaf(n2z[s], b1.z, b1.w)));
                        mn[s] = min3f(mn[s], r0, r1);
                    }
                }
                if (j < n) {
                    f4 b0 = lds[j];
#pragma unroll
                    for (int s = 0; s < TQ; ++s) {
                        float r0 = fmaf(n2x[s], b0.x, fmaf(n2y[s], b0.y, fmaf(n2z[s], b0.z, b0.w)));
                        mn[s] = fminf(mn[s], r0);
                    }
                }
            }
        };

        int lo = cb, hi = cb;
        scan_bucket(cb);
        while (true) {
            float slabL = ZMIN + lo * WB;
            float slabR = ZMIN + (hi + 1) * WB;
            bool needL = false, needR = false;
#pragma unroll
            for (int s = 0; s < TQ; ++s) {
                if (act[s]) {
                    float dcur = fmaxf(a2[s] + mn[s], 0.0f);
                    float dl = az[s] - slabL;   // >= 0 for in-range points
                    float dr = slabR - az[s];
                    needL |= (dl * dl < dcur);
                    needR |= (dr * dr < dcur);
                }
            }
            bool anyL = (lo > 0) && __any(needL);
            bool anyR = (hi < NB - 1) && __any(needR);
            if (!anyL && !anyR) break;
            if (anyL) { --lo; scan_bucket(lo); }
            if (anyR) { ++hi; scan_bucket(hi); }
        }

#pragma unroll
        for (int s = 0; s < TQ; ++s)
            if (act[s]) wsum += fmaxf(a2[s] + mn[s], 0.0f);
    }

    // wave-level sum, one atomic per wg
    for (int off = 32; off > 0; off >>= 1) wsum += __shfl_xor(wsum, off, 64);
    if (lane == 0) atomicAdd(&accf[0], wsum);
}

// ---------------- kernel 5: mask loss + final outputs ----------------
// accf[0]=cham_sum, accf[1]=pos_sum, accf[2]=neg_sum; acci[0]=pos_cnt, [1]=neg_cnt, [2]=done
__global__ void __launch_bounds__(256) final_k(const float* __restrict__ pm,
                                               const float* __restrict__ ms,
                                               float* __restrict__ accf,
                                               int* __restrict__ acci,
                                               float* __restrict__ out) {
    const int b = blockIdx.x;
    const int tid = threadIdx.x;
    __shared__ float ra[256], rb[256];
    __shared__ int ca[256], cb_[256];

    int base = b * MK_SEG;
    float ps = 0.0f, ns = 0.0f;
    int pc = 0, nc = 0;
    for (int i = tid; i < MK_SEG; i += 256) {
        float p = pm[base + i];
        p = fminf(fmaxf(p, 1e-7f), 1.0f - 1e-7f);
        float t = ms[base + i];
        if (t > 0.0f) {
            ps += -t * logf(p) * MASK_WGT;
            pc++;
        } else if (t == 0.0f) {
            ns += -logf(1.0f - p) * MASK_WGT;
            nc++;
        }
    }
    ra[tid] = ps; rb[tid] = ns; ca[tid] = pc; cb_[tid] = nc;
    __syncthreads();
    for (int w = 128; w > 0; w >>= 1) {
        if (tid < w) {
            ra[tid] += ra[tid + w];
            rb[tid] += rb[tid + w];
            ca[tid] += ca[tid + w];
            cb_[tid] += cb_[tid + w];
        }
        __syncthreads();
    }
    if (tid == 0) {
        atomicAdd(&accf[1], ra[0]);
        atomicAdd(&accf[2], rb[0]);
        atomicAdd(&acci[0], ca[0]);
        atomicAdd(&acci[1], cb_[0]);
        __threadfence();
        int old = __hip_atomic_fetch_add(&acci[2], 1, __ATOMIC_ACQ_REL,
                                         __HIP_MEMORY_SCOPE_AGENT);
        if (old == GB_MK - 1) {
            __threadfence();
            float cham = __hip_atomic_load(&accf[0], __ATOMIC_RELAXED, __HIP_MEMORY_SCOPE_AGENT);
            float pos  = __hip_atomic_load(&accf[1], __ATOMIC_RELAXED, __HIP_MEMORY_SCOPE_AGENT);
            float neg  = __hip_atomic_load(&accf[2], __ATOMIC_RELAXED, __HIP_MEMORY_SCOPE_AGENT);
            int cp = __hip_atomic_load(&acci[0], __ATOMIC_RELAXED, __HIP_MEMORY_SCOPE_AGENT);
            int cn = __hip_atomic_load(&acci[1], __ATOMIC_RELAXED, __HIP_MEMORY_SCOPE_AGENT);
            out[0] = cham * (1.0f / (float)NPTS);
            float loss = 0.0f;
            if (cp > 0) loss += pos / (float)cp;
            if (cn > 0) loss += neg / (float)cn;
            out[1] = loss;
        }
    }
}

// ---------------- launcher ----------------
extern "C" void kernel_launch(void* const* d_in, const int* in_sizes, int n_in,
                              void* d_out, int out_size, void* d_ws, size_t ws_size,
                              hipStream_t stream) {
    const float* pred_PM   = (const float*)d_in[0];
    const float* pred_Ms   = (const float*)d_in[1];
    const float* depth_src = (const float*)d_in[2];
    const float* depth_tgt = (const float*)d_in[3];
    float* out = (float*)d_out;

    // workspace layout
    f4* pts    = (f4*)d_ws;                      // 2*NPTS*16 = 614400 B
    f4* sorted = pts + 2 * NPTS;                 // 614400 B
    int* cnt   = (int*)(sorted + 2 * NPTS);      // 2*NB = 256
    int* cur   = cnt + 2 * NB;                   // 256
    int* offs  = cur + 2 * NB;                   // 2*(NB+1) = 258
    float* accf = (float*)(offs + 2 * (NB + 1)); // 3
    int* acci  = (int*)(accf + 3);               // 3

    init_k<<<1, 256, 0, stream>>>(cnt, cur, accf, acci);
    pts_hist_k<<<(2 * NPTS + 255) / 256, 256, 0, stream>>>(depth_src, depth_tgt,
                                                           pts, cnt);
    scan_k<<<1, 256, 0, stream>>>(cnt, offs, cur);
    scatter_k<<<(2 * NPTS + 255) / 256, 256, 0, stream>>>(pts, sorted, cur);
    chamfer_k<<<dim3(NB, 2, 2), 64, 0, stream>>>(sorted, offs, accf);
    final_k<<<GB_MK, 256, 0, stream>>>(pred_PM, pred_Ms, accf, acci, out);
}

// Round 9
// 80.902 us; speedup vs baseline: 1.2217x; 1.1159x over previous
//
#include <hip/hip_runtime.h>
#include <math.h>

// ---------------- problem constants ----------------
#define HH 120
#define WW 160
#define NPTS (HH * WW)            // 19200
#define FXC 572.4114f
#define FYC 573.57043f
#define CXC 325.2611f
#define CYC 242.04899f

// z-bucket grid (partition only -> correctness never depends on ZMIN/ZMAX)
#define NB 128
#define ZMIN 0.1f
#define ZMAX 2.1f
#define WB ((ZMAX - ZMIN) / NB)       // 0.015625
#define INVWB (NB / (ZMAX - ZMIN))    // 64.0

#define PAD 16                        // sentinel pad per cloud (overscan target)
#define CLOUD_STRIDE (NPTS + PAD)

#define MASK_WGT 1.3989422804014327f   // exp(0)*inv_sqrt_2pi + 1
#define GB_MK 16
#define MK_SEG (NPTS / GB_MK)     // 1200

typedef float __attribute__((ext_vector_type(4))) f4;

__device__ __forceinline__ void backproject_pt(int idx, float d,
                                               float& px, float& py, float& pz) {
    int y = idx / WW;
    int x = idx - y * WW;
    px = ((float)x - CXC) * d * (1.0f / FXC);
    py = ((float)y - CYC) * d * (1.0f / FYC);
    pz = d;
}

__device__ __forceinline__ float min3f(float a, float b, float c) {
    float d;
    asm("v_min3_f32 %0, %1, %2, %3" : "=v"(d) : "v"(a), "v"(b), "v"(c));
    return d;
}

__device__ __forceinline__ int zbucket(float z) {
    int b = (int)((z - ZMIN) * INVWB);
    return b < 0 ? 0 : (b > NB - 1 ? NB - 1 : b);
}

// ---------------- kernel 0: init counters + sentinel pads ----------------
__global__ void __launch_bounds__(256) init_k(int* __restrict__ cnt,
                                              int* __restrict__ cur,
                                              float* __restrict__ accf,
                                              int* __restrict__ acci,
                                              f4* __restrict__ sorted) {
    int t = threadIdx.x;
    cnt[t] = 0;           // 2*NB = 256
    cur[t] = 0;
    if (t < 3) { accf[t] = 0.0f; acci[t] = 0; }
    if (t < 2 * PAD) {
        int c = t >> 4, k = t & (PAD - 1);
        f4 s = {0.0f, 0.0f, 0.0f, 1e30f};   // b2 huge -> never wins a min
        sorted[c * CLOUD_STRIDE + NPTS + k] = s;
    }
}

// ---------------- kernel 1: backproject + z-histogram ----------------
__global__ void __launch_bounds__(256) pts_hist_k(const float* __restrict__ depth_src,
                                                  const float* __restrict__ depth_tgt,
                                                  f4* __restrict__ pts,
                                                  int* __restrict__ cnt) {
    int i = blockIdx.x * 256 + threadIdx.x;
    if (i >= 2 * NPTS) return;
    int dir = (i >= NPTS);
    int idx = i - dir * NPTS;
    float d = dir ? depth_tgt[idx] : depth_src[idx];
    float px, py, pz;
    backproject_pt(idx, d, px, py, pz);
    f4 v = {px, py, pz, fmaf(px, px, fmaf(py, py, pz * pz))};
    pts[i] = v;
    atomicAdd(&cnt[dir * NB + zbucket(pz)], 1);
}

// ---------------- kernel 2: exclusive prefix scan (per cloud) ----------------
__global__ void __launch_bounds__(256) scan_k(const int* __restrict__ cnt,
                                              int* __restrict__ offs,
                                              int* __restrict__ cur) {
    __shared__ int sc[256];
    int t = threadIdx.x;          // t = cloud*NB + b
    int seg = t & (NB - 1);
    int c = cnt[t];
    sc[t] = c;
    __syncthreads();
    for (int off = 1; off < NB; off <<= 1) {
        int add = (seg >= off) ? sc[t - off] : 0;
        __syncthreads();
        sc[t] += add;
        __syncthreads();
    }
    int cloud = t >> 7;
    int excl = sc[t] - c;
    offs[cloud * (NB + 1) + seg] = excl;
    cur[t] = excl;
    if (seg == NB - 1) offs[cloud * (NB + 1) + NB] = sc[t];
}

// ---------------- kernel 3: scatter into z-bucketed order ----------------
__global__ void __launch_bounds__(256) scatter_k(const f4* __restrict__ pts,
                                                 f4* __restrict__ sorted,
                                                 int* __restrict__ cur) {
    int i = blockIdx.x * 256 + threadIdx.x;
    if (i >= 2 * NPTS) return;
    int dir = (i >= NPTS);
    f4 p = pts[i];
    int b = zbucket(p.z);
    int pos = atomicAdd(&cur[dir * NB + b], 1);
    sorted[dir * CLOUD_STRIDE + pos] = p;
}

// ---------------- kernel 4: pruned chamfer ----------------
// grid: (NPTS/64, 2) = (query group, direction), block = 64 (1 wave).
// Each lane owns ONE query. Candidates read directly from global with
// wave-uniform addresses, 16-deep unrolled batches (no LDS, no barriers).
// Overscan to multiple-of-16 is safe: next bucket = valid candidates,
// cloud end = sentinel pad.
__global__ void __launch_bounds__(64) chamfer_k(const f4* __restrict__ sorted,
                                                const int* __restrict__ offs,
                                                float* __restrict__ accf) {
    const int lane = threadIdx.x;
    const int g = blockIdx.x;
    const int dir = blockIdx.y;

    const f4* SQ = sorted + dir * CLOUD_STRIDE;
    const f4* SB = sorted + (1 - dir) * CLOUD_STRIDE;
    const int* offB = offs + (1 - dir) * (NB + 1);

    f4 a = SQ[g * 64 + lane];
    const float n2x = -2.0f * a.x, n2y = -2.0f * a.y, n2z = -2.0f * a.z;
    const float az = a.z, a2 = a.w;
    float mnA = INFINITY, mnB = INFINITY;   // two independent min chains

    // wave-uniform bucket window of this query group
    int bl = zbucket(az), bh = bl;
    for (int off = 32; off; off >>= 1) {
        bl = min(bl, __shfl_xor(bl, off, 64));
        bh = max(bh, __shfl_xor(bh, off, 64));
    }

    auto scan16 = [&](int c0, int c1) {
        for (int j = c0; j < c1; j += 16) {
            f4 q[16];
#pragma unroll
            for (int k = 0; k < 16; ++k) q[k] = SB[j + k];
#pragma unroll
            for (int k = 0; k < 16; k += 4) {
                float r0 = fmaf(n2x, q[k+0].x, fmaf(n2y, q[k+0].y, fmaf(n2z, q[k+0].z, q[k+0].w)));
                float r1 = fmaf(n2x, q[k+1].x, fmaf(n2y, q[k+1].y, fmaf(n2z, q[k+1].z, q[k+1].w)));
                float r2 = fmaf(n2x, q[k+2].x, fmaf(n2y, q[k+2].y, fmaf(n2z, q[k+2].z, q[k+2].w)));
                float r3 = fmaf(n2x, q[k+3].x, fmaf(n2y, q[k+3].y, fmaf(n2z, q[k+3].z, q[k+3].w)));
                mnA = min3f(mnA, r0, r1);
                mnB = min3f(mnB, r2, r3);
            }
        }
    };

    scan16(offB[bl], offB[bh + 1]);

    int lo = bl, hi = bh;
    while (true) {
        float mn = fminf(mnA, mnB);
        float dcur = fmaxf(a2 + mn, 0.0f);
        float dl = az - (ZMIN + lo * WB);          // >= 0
        float dr = (ZMIN + (hi + 1) * WB) - az;    // >= 0
        bool needL = (dl * dl < dcur);
        bool needR = (dr * dr < dcur);
        bool anyL = (lo > 0) && __any(needL);
        bool anyR = (hi < NB - 1) && __any(needR);
        if (!anyL && !anyR) break;
        if (anyL) { --lo; scan16(offB[lo], offB[lo + 1]); }
        if (anyR) { ++hi; scan16(offB[hi], offB[hi + 1]); }
    }

    float w = fmaxf(a2 + fminf(mnA, mnB), 0.0f);
    for (int off = 32; off; off >>= 1) w += __shfl_xor(w, off, 64);
    if (lane == 0) atomicAdd(&accf[0], w);
}

// ---------------- kernel 5: mask loss + final outputs ----------------
// accf[0]=cham_sum, accf[1]=pos_sum, accf[2]=neg_sum; acci[0]=pos_cnt, [1]=neg_cnt, [2]=done
__global__ void __launch_bounds__(256) final_k(const float* __restrict__ pm,
                                               const float* __restrict__ ms,
                                               float* __restrict__ accf,
                                               int* __restrict__ acci,
                                               float* __restrict__ out) {
    const int b = blockIdx.x;
    const int tid = threadIdx.x;
    __shared__ float ra[256], rb[256];
    __shared__ int ca[256], cb_[256];

    int base = b * MK_SEG;
    float ps = 0.0f, ns = 0.0f;
    int pc = 0, nc = 0;
    for (int i = tid; i < MK_SEG; i += 256) {
        float p = pm[base + i];
        p = fminf(fmaxf(p, 1e-7f), 1.0f - 1e-7f);
        float t = ms[base + i];
        if (t > 0.0f) {
            ps += -t * logf(p) * MASK_WGT;
            pc++;
        } else if (t == 0.0f) {
            ns += -logf(1.0f - p) * MASK_WGT;
            nc++;
        }
    }
    ra[tid] = ps; rb[tid] = ns; ca[tid] = pc; cb_[tid] = nc;
    __syncthreads();
    for (int w = 128; w > 0; w >>= 1) {
        if (tid < w) {
            ra[tid] += ra[tid + w];
            rb[tid] += rb[tid + w];
            ca[tid] += ca[tid + w];
            cb_[tid] += cb_[tid + w];
        }
        __syncthreads();
    }
    if (tid == 0) {
        atomicAdd(&accf[1], ra[0]);
        atomicAdd(&accf[2], rb[0]);
        atomicAdd(&acci[0], ca[0]);
        atomicAdd(&acci[1], cb_[0]);
        __threadfence();
        int old = __hip_atomic_fetch_add(&acci[2], 1, __ATOMIC_ACQ_REL,
                                         __HIP_MEMORY_SCOPE_AGENT);
        if (old == GB_MK - 1) {
            __threadfence();
            float cham = __hip_atomic_load(&accf[0], __ATOMIC_RELAXED, __HIP_MEMORY_SCOPE_AGENT);
            float pos  = __hip_atomic_load(&accf[1], __ATOMIC_RELAXED, __HIP_MEMORY_SCOPE_AGENT);
            float neg  = __hip_atomic_load(&accf[2], __ATOMIC_RELAXED, __HIP_MEMORY_SCOPE_AGENT);
            int cp = __hip_atomic_load(&acci[0], __ATOMIC_RELAXED, __HIP_MEMORY_SCOPE_AGENT);
            int cn = __hip_atomic_load(&acci[1], __ATOMIC_RELAXED, __HIP_MEMORY_SCOPE_AGENT);
            out[0] = cham * (1.0f / (float)NPTS);
            float loss = 0.0f;
            if (cp > 0) loss += pos / (float)cp;
            if (cn > 0) loss += neg / (float)cn;
            out[1] = loss;
        }
    }
}

// ---------------- launcher ----------------
extern "C" void kernel_launch(void* const* d_in, const int* in_sizes, int n_in,
                              void* d_out, int out_size, void* d_ws, size_t ws_size,
                              hipStream_t stream) {
    const float* pred_PM   = (const float*)d_in[0];
    const float* pred_Ms   = (const float*)d_in[1];
    const float* depth_src = (const float*)d_in[2];
    const float* depth_tgt = (const float*)d_in[3];
    float* out = (float*)d_out;

    // workspace layout
    f4* pts    = (f4*)d_ws;                           // 2*NPTS*16      = 614400 B
    f4* sorted = pts + 2 * NPTS;                      // 2*(NPTS+16)*16 = 614912 B
    int* cnt   = (int*)(sorted + 2 * CLOUD_STRIDE);   // 2*NB
    int* cur   = cnt + 2 * NB;                        // 2*NB
    int* offs  = cur + 2 * NB;                        // 2*(NB+1)
    float* accf = (float*)(offs + 2 * (NB + 1));      // 3
    int* acci  = (int*)(accf + 3);                    // 3

    init_k<<<1, 256, 0, stream>>>(cnt, cur, accf, acci, sorted);
    pts_hist_k<<<(2 * NPTS + 255) / 256, 256, 0, stream>>>(depth_src, depth_tgt,
                                                           pts, cnt);
    scan_k<<<1, 256, 0, stream>>>(cnt, offs, cur);
    scatter_k<<<(2 * NPTS + 255) / 256, 256, 0, stream>>>(pts, sorted, cur);
    chamfer_k<<<dim3(NPTS / 64, 2), 64, 0, stream>>>(sorted, offs, accf);
    final_k<<<GB_MK, 256, 0, stream>>>(pred_PM, pred_Ms, accf, acci, out);
}